// Round 10
// baseline (260.317 us; speedup 1.0000x reference)
//
#include <hip/hip_runtime.h>
#include <hip/hip_bf16.h>
#include <cstdint>
#include <cstddef>

// ---------- types ----------
typedef short bf16x8 __attribute__((ext_vector_type(8)));   // 8 bf16 (4 VGPRs) MFMA A/B frag
typedef float floatx4 __attribute__((ext_vector_type(4)));  // MFMA C/D frag
typedef unsigned int uintx4 __attribute__((ext_vector_type(4)));
typedef unsigned short u16;

// Problem constants
constexpr int B = 4, S = 2048, D = 512, H = 8, DH = 64;
constexpr int M_ROWS = B * S;          // 8192
constexpr int D4 = 4 * D;              // 2048
// Q pre-scale: 1/sqrt(DH) * log2(e) so attention uses exp2 directly
constexpr float QSCALE = 0.18033688011112042f;

__device__ __forceinline__ u16 f2b(float f) {
  unsigned u = __builtin_bit_cast(unsigned, f);
  u += 0x7fff + ((u >> 16) & 1);       // RNE
  return (u16)(u >> 16);
}

__device__ __forceinline__ float b2f(u16 h) {
  return __builtin_bit_cast(float, (unsigned)h << 16);
}

__device__ __forceinline__ bf16x8 ldfrag(const u16* p) {
  return *reinterpret_cast<const bf16x8*>(p);
}

__device__ __forceinline__ floatx4 mfma16(bf16x8 a, bf16x8 b, floatx4 c) {
  return __builtin_amdgcn_mfma_f32_16x16x32_bf16(a, b, c, 0, 0, 0);
}

__device__ __forceinline__ ushort4 f2b4(float4 v) {
  ushort4 r;
  r.x = f2b(v.x); r.y = f2b(v.y); r.z = f2b(v.z); r.w = f2b(v.w);
  return r;
}

// async global->LDS, 16B per lane; LDS dest = wave-uniform base + lane*16
__device__ __forceinline__ void gld16(const u16* g, u16* l) {
  __builtin_amdgcn_global_load_lds(
      (const __attribute__((address_space(1))) void*)g,
      (__attribute__((address_space(3))) void*)l, 16, 0, 0);
}

// add 8 bf16 (16B aligned) into v[8]
__device__ __forceinline__ void add8bf(const u16* p, float* v) {
  const ushort4 h0 = *(const ushort4*)p, h1 = *(const ushort4*)(p + 4);
  v[0] += b2f(h0.x); v[1] += b2f(h0.y); v[2] += b2f(h0.z); v[3] += b2f(h0.w);
  v[4] += b2f(h1.x); v[5] += b2f(h1.y); v[6] += b2f(h1.z); v[7] += b2f(h1.w);
}

// ---------- single fused cast launch: x, W1, W2, Wq, Wk, Wv, Wo ----------
__global__ void cast_all_kernel(const float4* __restrict__ x,
                                const float4* __restrict__ w1, const float4* __restrict__ w2,
                                const float4* __restrict__ wq, const float4* __restrict__ wk,
                                const float4* __restrict__ wv, const float4* __restrict__ wo,
                                ushort4* __restrict__ xb,
                                ushort4* __restrict__ w1b, ushort4* __restrict__ w2b,
                                ushort4* __restrict__ wqb, ushort4* __restrict__ wkb,
                                ushort4* __restrict__ wvb, ushort4* __restrict__ wob) {
  int i = blockIdx.x * blockDim.x + threadIdx.x;
  constexpr int NX = (M_ROWS * D) / 4;   // 1048576
  constexpr int N1 = (D4 * D) / 4;       // 262144
  constexpr int NS = (D * D) / 4;        // 65536
  if (i < NX) { xb[i] = f2b4(x[i]); return; }
  i -= NX;
  if (i < N1) { w1b[i] = f2b4(w1[i]); return; }
  i -= N1;
  if (i < N1) { w2b[i] = f2b4(w2[i]); return; }
  i -= N1;
  const int sel = i >> 16, off = i & (NS - 1);
  const float4* src = sel == 0 ? wq : sel == 1 ? wk : sel == 2 ? wv : wo;
  ushort4* dst = sel == 0 ? wqb : sel == 1 ? wkb : sel == 2 ? wvb : wob;
  dst[off] = f2b4(src[off]);
}

// ---------- staged GEMM  y = A @ W.T ----------
// PIPE=1: 3-buffer counted-vmcnt pipeline. PIPE=0: 2-buffer __syncthreads path
// (mlp1: 4 blocks/CU already hides the drain via cross-block overlap, m114).
// EPI=0: plain output, EPI=1: +bias, relu. Both write bf16 (R7).
// R10: coalesced epilogue. The old path was 64 scalar 2-byte stores/thread
// (each wave-store = 4 scattered 32 B segments); at K=512 (16 iters) that
// epilogue is ~15-25% of block time. New: repack the 128x128 bf16 tile into
// LDS (reused staging buffer, octet-XOR-swizzled so quads land on disjoint
// bank groups), then 8x 16 B contiguous global stores per thread.
template <int EPI, int PIPE>
__global__ __launch_bounds__(256) void gemm_bt(
    const u16* __restrict__ A, const u16* __restrict__ W,
    const float* __restrict__ bias, void* __restrict__ out0, void* __restrict__ out1,
    int M, int N, int K, int klen) {
  __shared__ __align__(16) u16 As[PIPE ? 3 : 2][128 * 32];
  __shared__ __align__(16) u16 Bs[PIPE ? 3 : 2][128 * 32];
  const int wave = threadIdx.x >> 6, lane = threadIdx.x & 63;
  const int quad = lane >> 4, l16 = lane & 15;
  const int rowB = blockIdx.y * 128, colB = blockIdx.x * 128;
  const int rowW = (wave >> 1) * 64, colW = (wave & 1) * 64;
  const int koff = blockIdx.z * klen;
  void* out = blockIdx.z ? out1 : out0;

  floatx4 acc[4][4];
#pragma unroll
  for (int i = 0; i < 4; i++)
#pragma unroll
    for (int j = 0; j < 4; j++) acc[i][j] = (floatx4){0.f,0.f,0.f,0.f};

  const u16* gA = A + (size_t)(rowB + wave * 32 + (lane >> 2)) * K + koff + (lane & 3) * 8;
  const u16* gB = W + (size_t)(colB + wave * 32 + (lane >> 2)) * K + koff + (lane & 3) * 8;
  const int lds_off = wave * 1024;

  if constexpr (PIPE) {
    const int nt = klen / 32;
#pragma unroll
    for (int T = 0; T < 2; T++) {
      gld16(gA + T * 32,                    &As[T][lds_off]);
      gld16(gA + (size_t)16 * K + T * 32,   &As[T][lds_off + 512]);
      gld16(gB + T * 32,                    &Bs[T][lds_off]);
      gld16(gB + (size_t)16 * K + T * 32,   &Bs[T][lds_off + 512]);
    }
    int rb = 0, wb = 2;
    for (int it = 0; it < nt; ++it) {
      if (it + 1 < nt) asm volatile("s_waitcnt vmcnt(4)" ::: "memory");
      else             asm volatile("s_waitcnt vmcnt(0)" ::: "memory");
      __builtin_amdgcn_s_barrier();
      __builtin_amdgcn_sched_barrier(0);

      if (it + 2 < nt) {
        const int kc2 = (it + 2) * 32;
        gld16(gA + kc2,                    &As[wb][lds_off]);
        gld16(gA + (size_t)16 * K + kc2,   &As[wb][lds_off + 512]);
        gld16(gB + kc2,                    &Bs[wb][lds_off]);
        gld16(gB + (size_t)16 * K + kc2,   &Bs[wb][lds_off + 512]);
      }

      bf16x8 a[4], b[4];
#pragma unroll
      for (int i = 0; i < 4; i++)
        a[i] = ldfrag(&As[rb][(rowW + i * 16 + l16) * 32 + quad * 8]);
#pragma unroll
      for (int j = 0; j < 4; j++)
        b[j] = ldfrag(&Bs[rb][(colW + j * 16 + l16) * 32 + quad * 8]);
#pragma unroll
      for (int i = 0; i < 4; i++)
#pragma unroll
        for (int j = 0; j < 4; j++) acc[i][j] = mfma16(a[i], b[j], acc[i][j]);

      rb = rb == 2 ? 0 : rb + 1;
      wb = wb == 2 ? 0 : wb + 1;
    }
  } else {
#pragma unroll
    for (int rr = 0; rr < 2; rr++) {
      gld16(gA + (size_t)rr * 16 * K, &As[0][lds_off + rr * 512]);
      gld16(gB + (size_t)rr * 16 * K, &Bs[0][lds_off + rr * 512]);
    }

    int buf = 0;
    for (int kc = 0; kc < klen; kc += 32, buf ^= 1) {
      __syncthreads();

      if (kc + 32 < klen) {
#pragma unroll
        for (int rr = 0; rr < 2; rr++) {
          gld16(gA + (size_t)rr * 16 * K + kc + 32, &As[buf ^ 1][lds_off + rr * 512]);
          gld16(gB + (size_t)rr * 16 * K + kc + 32, &Bs[buf ^ 1][lds_off + rr * 512]);
        }
      }

      bf16x8 a[4], b[4];
#pragma unroll
      for (int i = 0; i < 4; i++)
        a[i] = ldfrag(&As[buf][(rowW + i * 16 + l16) * 32 + quad * 8]);
#pragma unroll
      for (int j = 0; j < 4; j++)
        b[j] = ldfrag(&Bs[buf][(colW + j * 16 + l16) * 32 + quad * 8]);
#pragma unroll
      for (int i = 0; i < 4; i++)
#pragma unroll
        for (int j = 0; j < 4; j++) acc[i][j] = mfma16(a[i], b[j], acc[i][j]);
    }
  }

  // ---- coalesced epilogue: acc -> LDS (swizzled) -> 16B/lane global stores
  __syncthreads();                      // all staging reads done; reuse As
  u16* obuf = (u16*)&As[0][0];          // 32 KB: [128 rows][128 cols]
#pragma unroll
  for (int i = 0; i < 4; i++) {
#pragma unroll
    for (int j = 0; j < 4; j++) {
      const int gn = colB + colW + j * 16 + l16;
      const float bv = (EPI == 1) ? bias[gn] : 0.f;
      const int col = colW + j * 16 + l16;
#pragma unroll
      for (int r = 0; r < 4; r++) {
        const int row = rowW + i * 16 + quad * 4 + r;
        float v = acc[i][j][r] + bv;
        if (EPI == 1) v = v > 0.f ? v : 0.f;
        // octet swizzle: per-instr quads -> disjoint octet pairs (2-way, free)
        const int oct = (col >> 3) ^ (((row >> 2) & 3) << 1);
        obuf[row * 128 + oct * 8 + (col & 7)] = f2b(v);
      }
    }
  }
  __syncthreads();
  {
    const int row = threadIdx.x >> 1, half = threadIdx.x & 1;
    u16* gout = (u16*)out + (size_t)(rowB + row) * N + colB + half * 64;
#pragma unroll
    for (int kk = 0; kk < 8; kk++) {
      const int c0 = half * 64 + kk * 8;
      const int oct = (c0 >> 3) ^ (((row >> 2) & 3) << 1);
      *reinterpret_cast<uintx4*>(gout + kk * 8) =
          *reinterpret_cast<const uintx4*>(&obuf[row * 128 + oct * 8]);
    }
  }
}

// ---------- staged fused QKV GEMM (3-buffer counted-vmcnt pipeline) ----------
// V is written KEY-PERMUTED within each aligned 64-key block:
//   slot sigma(k) holds key k,  sigma: [a b q1 q0 r1 r0] -> [a q1 q0 b r1 r0]
// sigma fixes bit5, so 32-key aligned tiles are preserved as sets -- the
// attention kernel may use 32- or 64-key tiles unchanged.
__global__ __launch_bounds__(256) void qkv_gemm(
    const u16* __restrict__ xb,
    const u16* __restrict__ wq, const u16* __restrict__ wk, const u16* __restrict__ wv,
    u16* __restrict__ q, u16* __restrict__ k, u16* __restrict__ vT) {
  __shared__ __align__(16) u16 As[3][128 * 32];
  __shared__ __align__(16) u16 Bs[3][128 * 32];
  const int which = blockIdx.z;
  const u16* __restrict__ W = which == 0 ? wq : (which == 1 ? wk : wv);
  const int wave = threadIdx.x >> 6, lane = threadIdx.x & 63;
  const int quad = lane >> 4, l16 = lane & 15;
  const int rowB = blockIdx.y * 128, colB = blockIdx.x * 128;
  const int rowW = (wave >> 1) * 64, colW = (wave & 1) * 64;

  floatx4 acc[4][4];
#pragma unroll
  for (int i = 0; i < 4; i++)
#pragma unroll
    for (int j = 0; j < 4; j++) acc[i][j] = (floatx4){0.f,0.f,0.f,0.f};

  const u16* gA = xb + (size_t)(rowB + wave * 32 + (lane >> 2)) * D + (lane & 3) * 8;
  const u16* gB = W + (size_t)(colB + wave * 32 + (lane >> 2)) * D + (lane & 3) * 8;
  const int lds_off = wave * 1024;

  constexpr int nt = D / 32;   // 16
#pragma unroll
  for (int T = 0; T < 2; T++) {
    gld16(gA + T * 32,                    &As[T][lds_off]);
    gld16(gA + (size_t)16 * D + T * 32,   &As[T][lds_off + 512]);
    gld16(gB + T * 32,                    &Bs[T][lds_off]);
    gld16(gB + (size_t)16 * D + T * 32,   &Bs[T][lds_off + 512]);
  }
  int rb = 0, wb = 2;
  for (int it = 0; it < nt; ++it) {
    if (it + 1 < nt) asm volatile("s_waitcnt vmcnt(4)" ::: "memory");
    else             asm volatile("s_waitcnt vmcnt(0)" ::: "memory");
    __builtin_amdgcn_s_barrier();
    __builtin_amdgcn_sched_barrier(0);

    if (it + 2 < nt) {
      const int kc2 = (it + 2) * 32;
      gld16(gA + kc2,                    &As[wb][lds_off]);
      gld16(gA + (size_t)16 * D + kc2,   &As[wb][lds_off + 512]);
      gld16(gB + kc2,                    &Bs[wb][lds_off]);
      gld16(gB + (size_t)16 * D + kc2,   &Bs[wb][lds_off + 512]);
    }

    bf16x8 a[4], b[4];
#pragma unroll
    for (int i = 0; i < 4; i++)
      a[i] = ldfrag(&As[rb][(rowW + i * 16 + l16) * 32 + quad * 8]);
#pragma unroll
    for (int j = 0; j < 4; j++)
      b[j] = ldfrag(&Bs[rb][(colW + j * 16 + l16) * 32 + quad * 8]);
#pragma unroll
    for (int i = 0; i < 4; i++)
#pragma unroll
      for (int j = 0; j < 4; j++) acc[i][j] = mfma16(a[i], b[j], acc[i][j]);

    rb = rb == 2 ? 0 : rb + 1;
    wb = wb == 2 ? 0 : wb + 1;
  }

  const float oscale = (which == 0) ? QSCALE : 1.0f;
  u16* dst01 = which == 0 ? q : k;
#pragma unroll
  for (int i = 0; i < 4; i++) {
#pragma unroll
    for (int j = 0; j < 4; j++) {
      const int gn = colB + colW + j * 16 + l16;   // output feature = h*64+dh
      const int h = gn >> 6, dh = gn & 63;
#pragma unroll
      for (int r = 0; r < 4; r++) {
        const int gm = rowB + rowW + i * 16 + quad * 4 + r;   // b*S + s
        const int bb = gm >> 11, s = gm & 2047;
        const u16 val = f2b(acc[i][j][r] * oscale);
        if (which < 2) {
          dst01[((((size_t)bb * H + h) * S) + s) * DH + dh] = val;
        } else {
          // sigma: keep bit5 + bits0-1; q=(s>>2)&3 -> bits3-4; b=(s>>4)&1 -> bit2
          const int sl = s & 63;
          const int sw = (s & ~63) | (sl & 35) | ((sl & 12) << 1) | ((sl & 16) >> 2);
          vT[((((size_t)bb * H + h) * DH) + dh) * S + sw] = val;
        }
      }
    }
  }
}

// ---------- flash attention: super-iteration (R9, 47 us) ----------
// Swapped QK^T, V key-perm -> P in registers, R8 octet swizzle (conflicts 65K),
// 2-tile super-iters over a 4-buffer ring (one vmcnt+barrier per 64 keys).
__global__ __launch_bounds__(512, 4) void attn_kernel(
    const u16* __restrict__ q, const u16* __restrict__ k,
    const u16* __restrict__ vT, u16* __restrict__ ctxb) {
  __shared__ __align__(16) u16 kvbuf[4][2][4096];   // [buf][khalf][K 2048 | V 2048] 64 KB
  __shared__ __align__(16) float ltb[2][4][32];     // [khalf][pair][query] 1 KB
  const int wave = threadIdx.x >> 6, lane = threadIdx.x & 63;
  const int quad = lane >> 4, l16 = lane & 15;
  const int pair = wave >> 1, khalf = wave & 1;
  // XCD swizzle: 64 consecutive blk per XCD -> 4 bh (2 MB K/V) per XCD L2
  const int blk = (blockIdx.x & 7) * 64 + (blockIdx.x >> 3);
  const int w = blk * 4 + pair;          // 32-query tile id (4 | 64 -> same bh)
  const int bh = w >> 6, qt = w & 63;
  const int bb = bh >> 3, h = bh & 7;

  // Q fragments (B operand of swapped QK): 32 queries
  const u16* qp = q + ((size_t)bh * S + qt * 32 + l16) * DH + quad * 8;
  bf16x8 qf[2][2];
#pragma unroll
  for (int t = 0; t < 2; t++) {
    qf[t][0] = ldfrag(qp + (size_t)t * 16 * DH);
    qf[t][1] = ldfrag(qp + (size_t)t * 16 * DH + 32);
  }

  // staging role: pair<2 -> K (ch = pair&1 selects dh 0-31 / 32-63 half),
  //               pair>=2 -> V (ch selects dh rows 0-31 / 32-63)
  // soct: bank-conflict pre-swizzle of the source octet (R8, verified 65x
  // conflict reduction): LDS slot s of row r holds global octet s^((r>>1)&3).
  const int ch = pair & 1;
  const int soct = ((lane & 3) ^ ((lane >> 3) & 3)) * 8;
  const u16 *g0, *g1;
  size_t gstride;
  int d0;
  if (pair < 2) {
    g0 = k + (size_t)bh * S * DH + (size_t)(khalf * 1024 + (lane >> 2)) * DH
           + ch * 32 + soct;
    g1 = g0 + (size_t)16 * DH;
    gstride = (size_t)32 * DH;
    d0 = ch * 1024;                      // K region [0,2048): lo | hi
  } else {
    g0 = vT + (size_t)bh * DH * S + (size_t)(ch * 32 + (lane >> 2)) * S
            + khalf * 1024 + soct;
    g1 = g0 + (size_t)16 * S;
    gstride = 32;
    d0 = 2048 + ch * 1024;               // V region [2048,4096)
  }

  floatx4 o[2][4];
#pragma unroll
  for (int t = 0; t < 2; t++)
#pragma unroll
    for (int c = 0; c < 4; c++) o[t][c] = (floatx4){0.f,0.f,0.f,0.f};
  float lacc[2] = {0.f, 0.f};

  // prologue: stage tiles 0,1 into bufs 0,1
  gld16(g0,           &kvbuf[0][khalf][d0]);
  gld16(g1,           &kvbuf[0][khalf][d0 + 512]);
  gld16(g0 + gstride, &kvbuf[1][khalf][d0]);
  gld16(g1 + gstride, &kvbuf[1][khalf][d0 + 512]);

  // read-side swizzled slot: quad ^ ((l16>>1)&3), uniform for all 8 fragments
  const int sq = (quad ^ ((l16 >> 1) & 3)) * 8;

  for (int it2 = 0; it2 < 16; ++it2) {
    // own 4 loads (tiles 2*it2, 2*it2+1) must land; they are a full super-iter
    // old so this drain is cheap. Barrier then publishes both tiles block-wide.
    asm volatile("s_waitcnt vmcnt(0)" ::: "memory");
    __builtin_amdgcn_s_barrier();
    __builtin_amdgcn_sched_barrier(0);
    const int b0 = (it2 & 1) * 2;        // this super-iter's bufs {b0, b0+1}

    if (it2 + 1 < 16) {                  // prefetch tiles 2*it2+2, 2*it2+3
      const size_t t2 = (size_t)(2 * it2 + 2);
      gld16(g0 + t2 * gstride,       &kvbuf[b0 ^ 2][khalf][d0]);
      gld16(g1 + t2 * gstride,       &kvbuf[b0 ^ 2][khalf][d0 + 512]);
      gld16(g0 + (t2 + 1) * gstride, &kvbuf[(b0 ^ 2) + 1][khalf][d0]);
      gld16(g1 + (t2 + 1) * gstride, &kvbuf[(b0 ^ 2) + 1][khalf][d0 + 512]);
    }

#pragma unroll
    for (int half = 0; half < 2; ++half) {
      const u16* Kb = &kvbuf[b0 + half][khalf][0];
      const u16* Vb = &kvbuf[b0 + half][khalf][2048];
      bf16x8 kf[4], vf[4];
      kf[0] = ldfrag(&Kb[l16 * 32 + sq]);               // keys 0-15, dh lo
      kf[1] = ldfrag(&Kb[1024 + l16 * 32 + sq]);        // keys 0-15, dh hi
      kf[2] = ldfrag(&Kb[(16 + l16) * 32 + sq]);        // keys 16-31, lo
      kf[3] = ldfrag(&Kb[1024 + (16 + l16) * 32 + sq]); // keys 16-31, hi
#pragma unroll
      for (int c = 0; c < 4; c++)
        vf[c] = ldfrag(&Vb[(c * 16 + l16) * 32 + sq]);  // dh c*16+l16

      // QK^T (swapped) -> exp2 -> in-register pack -> PV, per 16-query sub-tile
#pragma unroll
      for (int t = 0; t < 2; t++) {
        floatx4 sc[2];
#pragma unroll
        for (int i = 0; i < 2; i++) {
          floatx4 z = (floatx4){0.f,0.f,0.f,0.f};
          z = mfma16(kf[2 * i], qf[t][0], z);
          z = mfma16(kf[2 * i + 1], qf[t][1], z);
          sc[i] = z;   // P^T[key = i*16+quad*4+r][query = t*16+l16]
        }

        unsigned wd[4];
        float a = 0.f;
#pragma unroll
        for (int i = 0; i < 2; i++) {
          const float p0 = __builtin_amdgcn_exp2f(sc[i][0]);
          const float p1 = __builtin_amdgcn_exp2f(sc[i][1]);
          const float p2 = __builtin_amdgcn_exp2f(sc[i][2]);
          const float p3 = __builtin_amdgcn_exp2f(sc[i][3]);
          a += (p0 + p1) + (p2 + p3);
          wd[2 * i] = __builtin_amdgcn_perm(
              __builtin_bit_cast(unsigned, p1) + 0x8000u,
              __builtin_bit_cast(unsigned, p0) + 0x8000u, 0x07060302u);
          wd[2 * i + 1] = __builtin_amdgcn_perm(
              __builtin_bit_cast(unsigned, p3) + 0x8000u,
              __builtin_bit_cast(unsigned, p2) + 0x8000u, 0x07060302u);
        }
        lacc[t] += a;
        // V key-permuted at write time -> this IS the PV A-fragment (keys 0-31)
        const uintx4 lo4 = (uintx4){wd[0], wd[1], wd[2], wd[3]};
        const bf16x8 pa = __builtin_bit_cast(bf16x8, lo4);

#pragma unroll
        for (int c = 0; c < 4; c++)
          o[t][c] = mfma16(pa, vf[c], o[t][c]);
      }
    }
  }

  // per-wave l totals (sum over quads; lt[t] uniform across quads)
  float lt[2];
#pragma unroll
  for (int t = 0; t < 2; t++) {
    float l = lacc[t];
    l += __shfl_xor(l, 16);
    l += __shfl_xor(l, 32);
    lt[t] = l;
  }

  // additive key-half combine overlaid on dead kvbuf (32 KB <= 64 KB).
  // XOR slot swizzle breaks the one-column 64-way bank conflict.
  __syncthreads();   // all kvbuf reads (final tiles) complete before overwrite
  float* ob = reinterpret_cast<float*>(&kvbuf[0][0][0]) + pair * 2048;
  if (quad == 0) {
#pragma unroll
    for (int t = 0; t < 2; t++) ltb[khalf][pair][t * 16 + l16] = lt[t];
  }
  if (khalf == 1) {
#pragma unroll
    for (int t = 0; t < 2; t++)
#pragma unroll
      for (int c = 0; c < 4; c++) {
        const int idx = 4 * t + c;
        const int slot = (idx ^ (lane & 7)) & 7;
        *reinterpret_cast<floatx4*>(&ob[lane * 32 + slot * 4]) = o[t][c];
      }
  }
  __syncthreads();
  if (khalf == 0) {
    float inv[2][4];
#pragma unroll
    for (int t = 0; t < 2; t++)
#pragma unroll
      for (int r = 0; r < 4; r++)
        inv[t][r] = 1.0f / (ltb[0][pair][t * 16 + quad * 4 + r] +
                            ltb[1][pair][t * 16 + quad * 4 + r]);

    const size_t crow_base = ((size_t)bb * S) * D + h * DH;
#pragma unroll
    for (int t = 0; t < 2; t++)
#pragma unroll
      for (int c = 0; c < 4; c++) {
        const int idx = 4 * t + c;
        const int slot = (idx ^ (lane & 7)) & 7;
        const floatx4 oo = o[t][c] +
            *reinterpret_cast<const floatx4*>(&ob[lane * 32 + slot * 4]);
        const int dh = c * 16 + l16;
#pragma unroll
        for (int r = 0; r < 4; r++) {
          const int s = qt * 32 + t * 16 + quad * 4 + r;
          ctxb[crow_base + (size_t)s * D + dh] = f2b(oo[r] * inv[t][r]);
        }
      }
  }
}

// ---------- layernorm ----------
// ya/yb are bf16 partials (split-K GEMM outputs).
// MODE 0 (LN1): resid bf16 (xb), out = bf16 hb
// MODE 1 (LN2): resid bf16 (hb), + b2 pre-bias, out = fp32 d_out
template <int MODE>
__global__ __launch_bounds__(256) void ln_kernel(
    const void* __restrict__ resid, const u16* __restrict__ ya,
    const u16* __restrict__ yb, const float* __restrict__ pb,
    const float* __restrict__ g, const float* __restrict__ bvec,
    float* __restrict__ outF, u16* __restrict__ outB) {
  const int wave = threadIdx.x >> 6, lane = threadIdx.x & 63;
  const int row = blockIdx.x * 4 + wave;
  float v[8] = {0.f, 0.f, 0.f, 0.f, 0.f, 0.f, 0.f, 0.f};
  add8bf(ya + (size_t)row * D + lane * 8, v);
  add8bf(yb + (size_t)row * D + lane * 8, v);
  add8bf((const u16*)resid + (size_t)row * D + lane * 8, v);
  if (MODE == 1) {
    const float4 p0 = *(const float4*)(pb + lane * 8);
    const float4 p1 = *(const float4*)(pb + lane * 8 + 4);
    v[0] += p0.x; v[1] += p0.y; v[2] += p0.z; v[3] += p0.w;
    v[4] += p1.x; v[5] += p1.y; v[6] += p1.z; v[7] += p1.w;
  }
  float sum = 0.f;
#pragma unroll
  for (int i = 0; i < 8; i++) sum += v[i];
#pragma unroll
  for (int d = 1; d < 64; d <<= 1) sum += __shfl_xor(sum, d);
  const float mu = sum * (1.f / D);
  float vs = 0.f;
#pragma unroll
  for (int i = 0; i < 8; i++) { const float t = v[i] - mu; vs += t * t; }
#pragma unroll
  for (int d = 1; d < 64; d <<= 1) vs += __shfl_xor(vs, d);
  const float rstd = rsqrtf(vs * (1.f / D) + 1e-5f);
#pragma unroll
  for (int i = 0; i < 8; i++) {
    const int col = lane * 8 + i;
    const float o = (v[i] - mu) * rstd * g[col] + bvec[col];
    if (MODE == 0) outB[(size_t)row * D + col] = f2b(o);
    else           outF[(size_t)row * D + col] = o;
  }
}

// ---------- workspace layout (bytes) ----------
constexpr size_t OFF_XB  = 0;                       // 8 MB  xb [8192,512] bf16
constexpr size_t OFF_WQB = 8u << 20;                // 512 KB
constexpr size_t OFF_WKB = OFF_WQB + (512u << 10);
constexpr size_t OFF_WVB = OFF_WKB + (512u << 10);
constexpr size_t OFF_WOB = OFF_WVB + (512u << 10);
constexpr size_t OFF_W1B = 10u << 20;               // 2 MB
constexpr size_t OFF_W2B = 12u << 20;               // 2 MB
constexpr size_t OFF_Q   = 14u << 20;               // 8 MB  (reused as y1 bf16 after attn)
constexpr size_t OFF_K   = 22u << 20;               // 8 MB
constexpr size_t OFF_VT  = 30u << 20;               // 8 MB
constexpr size_t OFF_CTX = 38u << 20;               // 8 MB
constexpr size_t OFF_Y   = 46u << 20;               // 8 MB bf16 (y0)
constexpr size_t OFF_HB  = 78u << 20;               // 8 MB bf16 h
constexpr size_t OFF_M1B = 86u << 20;               // 32 MB bf16 [8192,2048]
// total 118 MB

extern "C" void kernel_launch(void* const* d_in, const int* in_sizes, int n_in,
                              void* d_out, int out_size, void* d_ws, size_t ws_size,
                              hipStream_t stream) {
  const float* x  = (const float*)d_in[0];
  const float* Wq = (const float*)d_in[1];
  const float* Wk = (const float*)d_in[2];
  const float* Wv = (const float*)d_in[3];
  const float* Wo = (const float*)d_in[4];
  const float* W1 = (const float*)d_in[5];
  const float* b1 = (const float*)d_in[6];
  const float* W2 = (const float*)d_in[7];
  const float* b2 = (const float*)d_in[8];
  const float* g1 = (const float*)d_in[9];
  const float* bb1 = (const float*)d_in[10];
  const float* g2 = (const float*)d_in[11];
  const float* bb2 = (const float*)d_in[12];

  char* ws = (char*)d_ws;
  u16* xb  = (u16*)(ws + OFF_XB);
  u16* wqb = (u16*)(ws + OFF_WQB);
  u16* wkb = (u16*)(ws + OFF_WKB);
  u16* wvb = (u16*)(ws + OFF_WVB);
  u16* wob = (u16*)(ws + OFF_WOB);
  u16* w1b = (u16*)(ws + OFF_W1B);
  u16* w2b = (u16*)(ws + OFF_W2B);
  u16* qb  = (u16*)(ws + OFF_Q);
  u16* kb  = (u16*)(ws + OFF_K);
  u16* vtb = (u16*)(ws + OFF_VT);
  u16* ctxb = (u16*)(ws + OFF_CTX);
  u16* y0 = (u16*)(ws + OFF_Y);
  u16* y1 = (u16*)(ws + OFF_Q);     // reuses q region (free after attention)
  u16* hb  = (u16*)(ws + OFF_HB);
  u16* m1b = (u16*)(ws + OFF_M1B);

  // 1. single fused cast launch (x + 6 weights)
  {
    const int n4 = (M_ROWS * D) / 4 + (D4 * D) / 4 * 2 + (D * D) / 4 * 4;  // 1835008
    cast_all_kernel<<<(n4 + 255) / 256, 256, 0, stream>>>(
        (const float4*)x, (const float4*)W1, (const float4*)W2, (const float4*)Wq,
        (const float4*)Wk, (const float4*)Wv, (const float4*)Wo,
        (ushort4*)xb, (ushort4*)w1b, (ushort4*)w2b, (ushort4*)wqb,
        (ushort4*)wkb, (ushort4*)wvb, (ushort4*)wob);
  }

  // 2. QKV projections (pipelined staging; q pre-scaled by QSCALE; V key-permuted)
  qkv_gemm<<<dim3(D / 128, M_ROWS / 128, 3), 256, 0, stream>>>(xb, wqb, wkb, wvb, qb, kb, vtb);

  // 3. attention: 512 blocks x 8 waves, 2 blocks/CU, 2-tile super-iterations
  attn_kernel<<<B * H * S / 32 / 4, 512, 0, stream>>>(qb, kb, vtb, ctxb);

  // 4. out-proj: split-K=2 -> y0,y1 bf16 partials; 512 blocks 2/CU (pipelined)
  gemm_bt<0, 1><<<dim3(D / 128, M_ROWS / 128, 2), 256, 0, stream>>>(
      ctxb, wob, nullptr, y0, y1, M_ROWS, D, D, D / 2);

  // 5. h = LN(xb + y0 + y1) -> bf16 hb
  ln_kernel<0><<<M_ROWS / 4, 256, 0, stream>>>(
      xb, y0, y1, nullptr, g1, bb1, nullptr, hb);

  // 6. m1 = relu(h @ W1.T + b1) -> bf16; 1024 blocks 4/CU
  gemm_bt<1, 0><<<dim3(D4 / 128, M_ROWS / 128, 1), 256, 0, stream>>>(
      hb, w1b, b1, m1b, nullptr, M_ROWS, D4, D, D);

  // 7. mlp partials: split-K=2 over K=2048 -> y0,y1 bf16; 512 blocks 2/CU
  gemm_bt<0, 1><<<dim3(D / 128, M_ROWS / 128, 2), 256, 0, stream>>>(
      m1b, w2b, nullptr, y0, y1, M_ROWS, D, D4, D4 / 2);

  // 8. out = LN(hb + y0 + y1 + b2)   (b2 folded in as pre-bias)
  ln_kernel<1><<<M_ROWS / 4, 256, 0, stream>>>(
      hb, y0, y1, b2, g2, bb2, (float*)d_out, nullptr);
}

// Round 11
// 247.337 us; speedup vs baseline: 1.0525x; 1.0525x over previous
//
#include <hip/hip_runtime.h>
#include <hip/hip_bf16.h>
#include <cstdint>
#include <cstddef>

// ---------- types ----------
typedef short bf16x8 __attribute__((ext_vector_type(8)));   // 8 bf16 (4 VGPRs) MFMA A/B frag
typedef float floatx4 __attribute__((ext_vector_type(4)));  // MFMA C/D frag
typedef unsigned int uintx4 __attribute__((ext_vector_type(4)));
typedef unsigned short u16;

// Problem constants
constexpr int B = 4, S = 2048, D = 512, H = 8, DH = 64;
constexpr int M_ROWS = B * S;          // 8192
constexpr int D4 = 4 * D;              // 2048
// Q pre-scale: 1/sqrt(DH) * log2(e) so attention uses exp2 directly
constexpr float QSCALE = 0.18033688011112042f;

__device__ __forceinline__ u16 f2b(float f) {
  unsigned u = __builtin_bit_cast(unsigned, f);
  u += 0x7fff + ((u >> 16) & 1);       // RNE
  return (u16)(u >> 16);
}

__device__ __forceinline__ float b2f(u16 h) {
  return __builtin_bit_cast(float, (unsigned)h << 16);
}

__device__ __forceinline__ bf16x8 ldfrag(const u16* p) {
  return *reinterpret_cast<const bf16x8*>(p);
}

__device__ __forceinline__ floatx4 mfma16(bf16x8 a, bf16x8 b, floatx4 c) {
  return __builtin_amdgcn_mfma_f32_16x16x32_bf16(a, b, c, 0, 0, 0);
}

__device__ __forceinline__ ushort4 f2b4(float4 v) {
  ushort4 r;
  r.x = f2b(v.x); r.y = f2b(v.y); r.z = f2b(v.z); r.w = f2b(v.w);
  return r;
}

// async global->LDS, 16B per lane; LDS dest = wave-uniform base + lane*16
__device__ __forceinline__ void gld16(const u16* g, u16* l) {
  __builtin_amdgcn_global_load_lds(
      (const __attribute__((address_space(1))) void*)g,
      (__attribute__((address_space(3))) void*)l, 16, 0, 0);
}

// add 8 bf16 (16B aligned) into v[8]
__device__ __forceinline__ void add8bf(const u16* p, float* v) {
  const ushort4 h0 = *(const ushort4*)p, h1 = *(const ushort4*)(p + 4);
  v[0] += b2f(h0.x); v[1] += b2f(h0.y); v[2] += b2f(h0.z); v[3] += b2f(h0.w);
  v[4] += b2f(h1.x); v[5] += b2f(h1.y); v[6] += b2f(h1.z); v[7] += b2f(h1.w);
}

// ---------- single fused cast launch: x, W1, W2, Wq, Wk, Wv, Wo ----------
__global__ void cast_all_kernel(const float4* __restrict__ x,
                                const float4* __restrict__ w1, const float4* __restrict__ w2,
                                const float4* __restrict__ wq, const float4* __restrict__ wk,
                                const float4* __restrict__ wv, const float4* __restrict__ wo,
                                ushort4* __restrict__ xb,
                                ushort4* __restrict__ w1b, ushort4* __restrict__ w2b,
                                ushort4* __restrict__ wqb, ushort4* __restrict__ wkb,
                                ushort4* __restrict__ wvb, ushort4* __restrict__ wob) {
  int i = blockIdx.x * blockDim.x + threadIdx.x;
  constexpr int NX = (M_ROWS * D) / 4;   // 1048576
  constexpr int N1 = (D4 * D) / 4;       // 262144
  constexpr int NS = (D * D) / 4;        // 65536
  if (i < NX) { xb[i] = f2b4(x[i]); return; }
  i -= NX;
  if (i < N1) { w1b[i] = f2b4(w1[i]); return; }
  i -= N1;
  if (i < N1) { w2b[i] = f2b4(w2[i]); return; }
  i -= N1;
  const int sel = i >> 16, off = i & (NS - 1);
  const float4* src = sel == 0 ? wq : sel == 1 ? wk : sel == 2 ? wv : wo;
  ushort4* dst = sel == 0 ? wqb : sel == 1 ? wkb : sel == 2 ? wvb : wob;
  dst[off] = f2b4(src[off]);
}

// ---------- staged GEMM  y = A @ W.T ----------
// PIPE=1: 3-buffer counted-vmcnt pipeline. PIPE=0: 2-buffer __syncthreads path
// (mlp1: 4 blocks/CU already hides the drain via cross-block overlap, m114).
// EPI=0: plain output, EPI=1: +bias, relu. Both write bf16 (R7: verified -5us).
// Epilogue: plain scalar stores. R10's LDS-repack "coalesced" epilogue
// REGRESSED ~8us: scattered 2B global stores are fire-and-forget (no wave
// stall), while the repack added on-critical-path ds_writes + 2 barriers.
template <int EPI, int PIPE>
__global__ __launch_bounds__(256) void gemm_bt(
    const u16* __restrict__ A, const u16* __restrict__ W,
    const float* __restrict__ bias, void* __restrict__ out0, void* __restrict__ out1,
    int M, int N, int K, int klen) {
  __shared__ __align__(16) u16 As[PIPE ? 3 : 2][128 * 32];
  __shared__ __align__(16) u16 Bs[PIPE ? 3 : 2][128 * 32];
  const int wave = threadIdx.x >> 6, lane = threadIdx.x & 63;
  const int quad = lane >> 4, l16 = lane & 15;
  const int rowB = blockIdx.y * 128, colB = blockIdx.x * 128;
  const int rowW = (wave >> 1) * 64, colW = (wave & 1) * 64;
  const int koff = blockIdx.z * klen;
  void* out = blockIdx.z ? out1 : out0;

  floatx4 acc[4][4];
#pragma unroll
  for (int i = 0; i < 4; i++)
#pragma unroll
    for (int j = 0; j < 4; j++) acc[i][j] = (floatx4){0.f,0.f,0.f,0.f};

  const u16* gA = A + (size_t)(rowB + wave * 32 + (lane >> 2)) * K + koff + (lane & 3) * 8;
  const u16* gB = W + (size_t)(colB + wave * 32 + (lane >> 2)) * K + koff + (lane & 3) * 8;
  const int lds_off = wave * 1024;

  if constexpr (PIPE) {
    const int nt = klen / 32;
#pragma unroll
    for (int T = 0; T < 2; T++) {
      gld16(gA + T * 32,                    &As[T][lds_off]);
      gld16(gA + (size_t)16 * K + T * 32,   &As[T][lds_off + 512]);
      gld16(gB + T * 32,                    &Bs[T][lds_off]);
      gld16(gB + (size_t)16 * K + T * 32,   &Bs[T][lds_off + 512]);
    }
    int rb = 0, wb = 2;
    for (int it = 0; it < nt; ++it) {
      if (it + 1 < nt) asm volatile("s_waitcnt vmcnt(4)" ::: "memory");
      else             asm volatile("s_waitcnt vmcnt(0)" ::: "memory");
      __builtin_amdgcn_s_barrier();
      __builtin_amdgcn_sched_barrier(0);

      if (it + 2 < nt) {
        const int kc2 = (it + 2) * 32;
        gld16(gA + kc2,                    &As[wb][lds_off]);
        gld16(gA + (size_t)16 * K + kc2,   &As[wb][lds_off + 512]);
        gld16(gB + kc2,                    &Bs[wb][lds_off]);
        gld16(gB + (size_t)16 * K + kc2,   &Bs[wb][lds_off + 512]);
      }

      bf16x8 a[4], b[4];
#pragma unroll
      for (int i = 0; i < 4; i++)
        a[i] = ldfrag(&As[rb][(rowW + i * 16 + l16) * 32 + quad * 8]);
#pragma unroll
      for (int j = 0; j < 4; j++)
        b[j] = ldfrag(&Bs[rb][(colW + j * 16 + l16) * 32 + quad * 8]);
#pragma unroll
      for (int i = 0; i < 4; i++)
#pragma unroll
        for (int j = 0; j < 4; j++) acc[i][j] = mfma16(a[i], b[j], acc[i][j]);

      rb = rb == 2 ? 0 : rb + 1;
      wb = wb == 2 ? 0 : wb + 1;
    }
  } else {
#pragma unroll
    for (int rr = 0; rr < 2; rr++) {
      gld16(gA + (size_t)rr * 16 * K, &As[0][lds_off + rr * 512]);
      gld16(gB + (size_t)rr * 16 * K, &Bs[0][lds_off + rr * 512]);
    }

    int buf = 0;
    for (int kc = 0; kc < klen; kc += 32, buf ^= 1) {
      __syncthreads();

      if (kc + 32 < klen) {
#pragma unroll
        for (int rr = 0; rr < 2; rr++) {
          gld16(gA + (size_t)rr * 16 * K + kc + 32, &As[buf ^ 1][lds_off + rr * 512]);
          gld16(gB + (size_t)rr * 16 * K + kc + 32, &Bs[buf ^ 1][lds_off + rr * 512]);
        }
      }

      bf16x8 a[4], b[4];
#pragma unroll
      for (int i = 0; i < 4; i++)
        a[i] = ldfrag(&As[buf][(rowW + i * 16 + l16) * 32 + quad * 8]);
#pragma unroll
      for (int j = 0; j < 4; j++)
        b[j] = ldfrag(&Bs[buf][(colW + j * 16 + l16) * 32 + quad * 8]);
#pragma unroll
      for (int i = 0; i < 4; i++)
#pragma unroll
        for (int j = 0; j < 4; j++) acc[i][j] = mfma16(a[i], b[j], acc[i][j]);
    }
  }

#pragma unroll
  for (int i = 0; i < 4; i++) {
#pragma unroll
    for (int j = 0; j < 4; j++) {
      const int gn = colB + colW + j * 16 + l16;
      const float bv = (EPI == 1) ? bias[gn] : 0.f;
#pragma unroll
      for (int r = 0; r < 4; r++) {
        const int gm = rowB + rowW + i * 16 + quad * 4 + r;
        float v = acc[i][j][r] + bv;
        if (EPI == 1) v = v > 0.f ? v : 0.f;
        ((u16*)out)[(size_t)gm * N + gn] = f2b(v);
      }
    }
  }
}

// ---------- staged fused QKV GEMM (3-buffer counted-vmcnt pipeline) ----------
// V is written KEY-PERMUTED within each aligned 64-key block:
//   slot sigma(k) holds key k,  sigma: [a b q1 q0 r1 r0] -> [a q1 q0 b r1 r0]
// sigma fixes bit5, so 32-key aligned tiles are preserved as sets -- the
// attention kernel may use 32- or 64-key tiles unchanged.
__global__ __launch_bounds__(256) void qkv_gemm(
    const u16* __restrict__ xb,
    const u16* __restrict__ wq, const u16* __restrict__ wk, const u16* __restrict__ wv,
    u16* __restrict__ q, u16* __restrict__ k, u16* __restrict__ vT) {
  __shared__ __align__(16) u16 As[3][128 * 32];
  __shared__ __align__(16) u16 Bs[3][128 * 32];
  const int which = blockIdx.z;
  const u16* __restrict__ W = which == 0 ? wq : (which == 1 ? wk : wv);
  const int wave = threadIdx.x >> 6, lane = threadIdx.x & 63;
  const int quad = lane >> 4, l16 = lane & 15;
  const int rowB = blockIdx.y * 128, colB = blockIdx.x * 128;
  const int rowW = (wave >> 1) * 64, colW = (wave & 1) * 64;

  floatx4 acc[4][4];
#pragma unroll
  for (int i = 0; i < 4; i++)
#pragma unroll
    for (int j = 0; j < 4; j++) acc[i][j] = (floatx4){0.f,0.f,0.f,0.f};

  const u16* gA = xb + (size_t)(rowB + wave * 32 + (lane >> 2)) * D + (lane & 3) * 8;
  const u16* gB = W + (size_t)(colB + wave * 32 + (lane >> 2)) * D + (lane & 3) * 8;
  const int lds_off = wave * 1024;

  constexpr int nt = D / 32;   // 16
#pragma unroll
  for (int T = 0; T < 2; T++) {
    gld16(gA + T * 32,                    &As[T][lds_off]);
    gld16(gA + (size_t)16 * D + T * 32,   &As[T][lds_off + 512]);
    gld16(gB + T * 32,                    &Bs[T][lds_off]);
    gld16(gB + (size_t)16 * D + T * 32,   &Bs[T][lds_off + 512]);
  }
  int rb = 0, wb = 2;
  for (int it = 0; it < nt; ++it) {
    if (it + 1 < nt) asm volatile("s_waitcnt vmcnt(4)" ::: "memory");
    else             asm volatile("s_waitcnt vmcnt(0)" ::: "memory");
    __builtin_amdgcn_s_barrier();
    __builtin_amdgcn_sched_barrier(0);

    if (it + 2 < nt) {
      const int kc2 = (it + 2) * 32;
      gld16(gA + kc2,                    &As[wb][lds_off]);
      gld16(gA + (size_t)16 * D + kc2,   &As[wb][lds_off + 512]);
      gld16(gB + kc2,                    &Bs[wb][lds_off]);
      gld16(gB + (size_t)16 * D + kc2,   &Bs[wb][lds_off + 512]);
    }

    bf16x8 a[4], b[4];
#pragma unroll
    for (int i = 0; i < 4; i++)
      a[i] = ldfrag(&As[rb][(rowW + i * 16 + l16) * 32 + quad * 8]);
#pragma unroll
    for (int j = 0; j < 4; j++)
      b[j] = ldfrag(&Bs[rb][(colW + j * 16 + l16) * 32 + quad * 8]);
#pragma unroll
    for (int i = 0; i < 4; i++)
#pragma unroll
      for (int j = 0; j < 4; j++) acc[i][j] = mfma16(a[i], b[j], acc[i][j]);

    rb = rb == 2 ? 0 : rb + 1;
    wb = wb == 2 ? 0 : wb + 1;
  }

  const float oscale = (which == 0) ? QSCALE : 1.0f;
  u16* dst01 = which == 0 ? q : k;
#pragma unroll
  for (int i = 0; i < 4; i++) {
#pragma unroll
    for (int j = 0; j < 4; j++) {
      const int gn = colB + colW + j * 16 + l16;   // output feature = h*64+dh
      const int h = gn >> 6, dh = gn & 63;
#pragma unroll
      for (int r = 0; r < 4; r++) {
        const int gm = rowB + rowW + i * 16 + quad * 4 + r;   // b*S + s
        const int bb = gm >> 11, s = gm & 2047;
        const u16 val = f2b(acc[i][j][r] * oscale);
        if (which < 2) {
          dst01[((((size_t)bb * H + h) * S) + s) * DH + dh] = val;
        } else {
          // sigma: keep bit5 + bits0-1; q=(s>>2)&3 -> bits3-4; b=(s>>4)&1 -> bit2
          const int sl = s & 63;
          const int sw = (s & ~63) | (sl & 35) | ((sl & 12) << 1) | ((sl & 16) >> 2);
          vT[((((size_t)bb * H + h) * DH) + dh) * S + sw] = val;
        }
      }
    }
  }
}

// ---------- flash attention: super-iteration (R9, 47 us verified) ----------
// Swapped QK^T, V key-perm -> P in registers, R8 octet swizzle (conflicts 65K),
// 2-tile super-iters over a 4-buffer ring (one vmcnt+barrier per 64 keys).
__global__ __launch_bounds__(512, 4) void attn_kernel(
    const u16* __restrict__ q, const u16* __restrict__ k,
    const u16* __restrict__ vT, u16* __restrict__ ctxb) {
  __shared__ __align__(16) u16 kvbuf[4][2][4096];   // [buf][khalf][K 2048 | V 2048] 64 KB
  __shared__ __align__(16) float ltb[2][4][32];     // [khalf][pair][query] 1 KB
  const int wave = threadIdx.x >> 6, lane = threadIdx.x & 63;
  const int quad = lane >> 4, l16 = lane & 15;
  const int pair = wave >> 1, khalf = wave & 1;
  // XCD swizzle: 64 consecutive blk per XCD -> 4 bh (2 MB K/V) per XCD L2
  const int blk = (blockIdx.x & 7) * 64 + (blockIdx.x >> 3);
  const int w = blk * 4 + pair;          // 32-query tile id (4 | 64 -> same bh)
  const int bh = w >> 6, qt = w & 63;
  const int bb = bh >> 3, h = bh & 7;

  // Q fragments (B operand of swapped QK): 32 queries
  const u16* qp = q + ((size_t)bh * S + qt * 32 + l16) * DH + quad * 8;
  bf16x8 qf[2][2];
#pragma unroll
  for (int t = 0; t < 2; t++) {
    qf[t][0] = ldfrag(qp + (size_t)t * 16 * DH);
    qf[t][1] = ldfrag(qp + (size_t)t * 16 * DH + 32);
  }

  // staging role: pair<2 -> K (ch = pair&1 selects dh 0-31 / 32-63 half),
  //               pair>=2 -> V (ch selects dh rows 0-31 / 32-63)
  // soct: bank-conflict pre-swizzle of the source octet (R8, verified 65x
  // conflict reduction): LDS slot s of row r holds global octet s^((r>>1)&3).
  const int ch = pair & 1;
  const int soct = ((lane & 3) ^ ((lane >> 3) & 3)) * 8;
  const u16 *g0, *g1;
  size_t gstride;
  int d0;
  if (pair < 2) {
    g0 = k + (size_t)bh * S * DH + (size_t)(khalf * 1024 + (lane >> 2)) * DH
           + ch * 32 + soct;
    g1 = g0 + (size_t)16 * DH;
    gstride = (size_t)32 * DH;
    d0 = ch * 1024;                      // K region [0,2048): lo | hi
  } else {
    g0 = vT + (size_t)bh * DH * S + (size_t)(ch * 32 + (lane >> 2)) * S
            + khalf * 1024 + soct;
    g1 = g0 + (size_t)16 * S;
    gstride = 32;
    d0 = 2048 + ch * 1024;               // V region [2048,4096)
  }

  floatx4 o[2][4];
#pragma unroll
  for (int t = 0; t < 2; t++)
#pragma unroll
    for (int c = 0; c < 4; c++) o[t][c] = (floatx4){0.f,0.f,0.f,0.f};
  float lacc[2] = {0.f, 0.f};

  // prologue: stage tiles 0,1 into bufs 0,1
  gld16(g0,           &kvbuf[0][khalf][d0]);
  gld16(g1,           &kvbuf[0][khalf][d0 + 512]);
  gld16(g0 + gstride, &kvbuf[1][khalf][d0]);
  gld16(g1 + gstride, &kvbuf[1][khalf][d0 + 512]);

  // read-side swizzled slot: quad ^ ((l16>>1)&3), uniform for all 8 fragments
  const int sq = (quad ^ ((l16 >> 1) & 3)) * 8;

  for (int it2 = 0; it2 < 16; ++it2) {
    // own 4 loads (tiles 2*it2, 2*it2+1) must land; they are a full super-iter
    // old so this drain is cheap. Barrier then publishes both tiles block-wide.
    asm volatile("s_waitcnt vmcnt(0)" ::: "memory");
    __builtin_amdgcn_s_barrier();
    __builtin_amdgcn_sched_barrier(0);
    const int b0 = (it2 & 1) * 2;        // this super-iter's bufs {b0, b0+1}

    if (it2 + 1 < 16) {                  // prefetch tiles 2*it2+2, 2*it2+3
      const size_t t2 = (size_t)(2 * it2 + 2);
      gld16(g0 + t2 * gstride,       &kvbuf[b0 ^ 2][khalf][d0]);
      gld16(g1 + t2 * gstride,       &kvbuf[b0 ^ 2][khalf][d0 + 512]);
      gld16(g0 + (t2 + 1) * gstride, &kvbuf[(b0 ^ 2) + 1][khalf][d0]);
      gld16(g1 + (t2 + 1) * gstride, &kvbuf[(b0 ^ 2) + 1][khalf][d0 + 512]);
    }

#pragma unroll
    for (int half = 0; half < 2; ++half) {
      const u16* Kb = &kvbuf[b0 + half][khalf][0];
      const u16* Vb = &kvbuf[b0 + half][khalf][2048];
      bf16x8 kf[4], vf[4];
      kf[0] = ldfrag(&Kb[l16 * 32 + sq]);               // keys 0-15, dh lo
      kf[1] = ldfrag(&Kb[1024 + l16 * 32 + sq]);        // keys 0-15, dh hi
      kf[2] = ldfrag(&Kb[(16 + l16) * 32 + sq]);        // keys 16-31, lo
      kf[3] = ldfrag(&Kb[1024 + (16 + l16) * 32 + sq]); // keys 16-31, hi
#pragma unroll
      for (int c = 0; c < 4; c++)
        vf[c] = ldfrag(&Vb[(c * 16 + l16) * 32 + sq]);  // dh c*16+l16

      // QK^T (swapped) -> exp2 -> in-register pack -> PV, per 16-query sub-tile
#pragma unroll
      for (int t = 0; t < 2; t++) {
        floatx4 sc[2];
#pragma unroll
        for (int i = 0; i < 2; i++) {
          floatx4 z = (floatx4){0.f,0.f,0.f,0.f};
          z = mfma16(kf[2 * i], qf[t][0], z);
          z = mfma16(kf[2 * i + 1], qf[t][1], z);
          sc[i] = z;   // P^T[key = i*16+quad*4+r][query = t*16+l16]
        }

        unsigned wd[4];
        float a = 0.f;
#pragma unroll
        for (int i = 0; i < 2; i++) {
          const float p0 = __builtin_amdgcn_exp2f(sc[i][0]);
          const float p1 = __builtin_amdgcn_exp2f(sc[i][1]);
          const float p2 = __builtin_amdgcn_exp2f(sc[i][2]);
          const float p3 = __builtin_amdgcn_exp2f(sc[i][3]);
          a += (p0 + p1) + (p2 + p3);
          wd[2 * i] = __builtin_amdgcn_perm(
              __builtin_bit_cast(unsigned, p1) + 0x8000u,
              __builtin_bit_cast(unsigned, p0) + 0x8000u, 0x07060302u);
          wd[2 * i + 1] = __builtin_amdgcn_perm(
              __builtin_bit_cast(unsigned, p3) + 0x8000u,
              __builtin_bit_cast(unsigned, p2) + 0x8000u, 0x07060302u);
        }
        lacc[t] += a;
        // V key-permuted at write time -> this IS the PV A-fragment (keys 0-31)
        const uintx4 lo4 = (uintx4){wd[0], wd[1], wd[2], wd[3]};
        const bf16x8 pa = __builtin_bit_cast(bf16x8, lo4);

#pragma unroll
        for (int c = 0; c < 4; c++)
          o[t][c] = mfma16(pa, vf[c], o[t][c]);
      }
    }
  }

  // per-wave l totals (sum over quads; lt[t] uniform across quads)
  float lt[2];
#pragma unroll
  for (int t = 0; t < 2; t++) {
    float l = lacc[t];
    l += __shfl_xor(l, 16);
    l += __shfl_xor(l, 32);
    lt[t] = l;
  }

  // additive key-half combine overlaid on dead kvbuf (32 KB <= 64 KB).
  // XOR slot swizzle breaks the one-column 64-way bank conflict.
  __syncthreads();   // all kvbuf reads (final tiles) complete before overwrite
  float* ob = reinterpret_cast<float*>(&kvbuf[0][0][0]) + pair * 2048;
  if (quad == 0) {
#pragma unroll
    for (int t = 0; t < 2; t++) ltb[khalf][pair][t * 16 + l16] = lt[t];
  }
  if (khalf == 1) {
#pragma unroll
    for (int t = 0; t < 2; t++)
#pragma unroll
      for (int c = 0; c < 4; c++) {
        const int idx = 4 * t + c;
        const int slot = (idx ^ (lane & 7)) & 7;
        *reinterpret_cast<floatx4*>(&ob[lane * 32 + slot * 4]) = o[t][c];
      }
  }
  __syncthreads();
  if (khalf == 0) {
    float inv[2][4];
#pragma unroll
    for (int t = 0; t < 2; t++)
#pragma unroll
      for (int r = 0; r < 4; r++)
        inv[t][r] = 1.0f / (ltb[0][pair][t * 16 + quad * 4 + r] +
                            ltb[1][pair][t * 16 + quad * 4 + r]);

    const size_t crow_base = ((size_t)bb * S) * D + h * DH;
#pragma unroll
    for (int t = 0; t < 2; t++)
#pragma unroll
      for (int c = 0; c < 4; c++) {
        const int idx = 4 * t + c;
        const int slot = (idx ^ (lane & 7)) & 7;
        const floatx4 oo = o[t][c] +
            *reinterpret_cast<const floatx4*>(&ob[lane * 32 + slot * 4]);
        const int dh = c * 16 + l16;
#pragma unroll
        for (int r = 0; r < 4; r++) {
          const int s = qt * 32 + t * 16 + quad * 4 + r;
          ctxb[crow_base + (size_t)s * D + dh] = f2b(oo[r] * inv[t][r]);
        }
      }
  }
}

// ---------- layernorm ----------
// ya/yb are bf16 partials (split-K GEMM outputs).
// MODE 0 (LN1): resid bf16 (xb), out = bf16 hb
// MODE 1 (LN2): resid bf16 (hb), + b2 pre-bias, out = fp32 d_out
template <int MODE>
__global__ __launch_bounds__(256) void ln_kernel(
    const void* __restrict__ resid, const u16* __restrict__ ya,
    const u16* __restrict__ yb, const float* __restrict__ pb,
    const float* __restrict__ g, const float* __restrict__ bvec,
    float* __restrict__ outF, u16* __restrict__ outB) {
  const int wave = threadIdx.x >> 6, lane = threadIdx.x & 63;
  const int row = blockIdx.x * 4 + wave;
  float v[8] = {0.f, 0.f, 0.f, 0.f, 0.f, 0.f, 0.f, 0.f};
  add8bf(ya + (size_t)row * D + lane * 8, v);
  add8bf(yb + (size_t)row * D + lane * 8, v);
  add8bf((const u16*)resid + (size_t)row * D + lane * 8, v);
  if (MODE == 1) {
    const float4 p0 = *(const float4*)(pb + lane * 8);
    const float4 p1 = *(const float4*)(pb + lane * 8 + 4);
    v[0] += p0.x; v[1] += p0.y; v[2] += p0.z; v[3] += p0.w;
    v[4] += p1.x; v[5] += p1.y; v[6] += p1.z; v[7] += p1.w;
  }
  float sum = 0.f;
#pragma unroll
  for (int i = 0; i < 8; i++) sum += v[i];
#pragma unroll
  for (int d = 1; d < 64; d <<= 1) sum += __shfl_xor(sum, d);
  const float mu = sum * (1.f / D);
  float vs = 0.f;
#pragma unroll
  for (int i = 0; i < 8; i++) { const float t = v[i] - mu; vs += t * t; }
#pragma unroll
  for (int d = 1; d < 64; d <<= 1) vs += __shfl_xor(vs, d);
  const float rstd = rsqrtf(vs * (1.f / D) + 1e-5f);
#pragma unroll
  for (int i = 0; i < 8; i++) {
    const int col = lane * 8 + i;
    const float o = (v[i] - mu) * rstd * g[col] + bvec[col];
    if (MODE == 0) outB[(size_t)row * D + col] = f2b(o);
    else           outF[(size_t)row * D + col] = o;
  }
}

// ---------- workspace layout (bytes) ----------
constexpr size_t OFF_XB  = 0;                       // 8 MB  xb [8192,512] bf16
constexpr size_t OFF_WQB = 8u << 20;                // 512 KB
constexpr size_t OFF_WKB = OFF_WQB + (512u << 10);
constexpr size_t OFF_WVB = OFF_WKB + (512u << 10);
constexpr size_t OFF_WOB = OFF_WVB + (512u << 10);
constexpr size_t OFF_W1B = 10u << 20;               // 2 MB
constexpr size_t OFF_W2B = 12u << 20;               // 2 MB
constexpr size_t OFF_Q   = 14u << 20;               // 8 MB  (reused as y1 bf16 after attn)
constexpr size_t OFF_K   = 22u << 20;               // 8 MB
constexpr size_t OFF_VT  = 30u << 20;               // 8 MB
constexpr size_t OFF_CTX = 38u << 20;               // 8 MB
constexpr size_t OFF_Y   = 46u << 20;               // 8 MB bf16 (y0)
constexpr size_t OFF_HB  = 78u << 20;               // 8 MB bf16 h
constexpr size_t OFF_M1B = 86u << 20;               // 32 MB bf16 [8192,2048]
// total 118 MB

extern "C" void kernel_launch(void* const* d_in, const int* in_sizes, int n_in,
                              void* d_out, int out_size, void* d_ws, size_t ws_size,
                              hipStream_t stream) {
  const float* x  = (const float*)d_in[0];
  const float* Wq = (const float*)d_in[1];
  const float* Wk = (const float*)d_in[2];
  const float* Wv = (const float*)d_in[3];
  const float* Wo = (const float*)d_in[4];
  const float* W1 = (const float*)d_in[5];
  const float* b1 = (const float*)d_in[6];
  const float* W2 = (const float*)d_in[7];
  const float* b2 = (const float*)d_in[8];
  const float* g1 = (const float*)d_in[9];
  const float* bb1 = (const float*)d_in[10];
  const float* g2 = (const float*)d_in[11];
  const float* bb2 = (const float*)d_in[12];

  char* ws = (char*)d_ws;
  u16* xb  = (u16*)(ws + OFF_XB);
  u16* wqb = (u16*)(ws + OFF_WQB);
  u16* wkb = (u16*)(ws + OFF_WKB);
  u16* wvb = (u16*)(ws + OFF_WVB);
  u16* wob = (u16*)(ws + OFF_WOB);
  u16* w1b = (u16*)(ws + OFF_W1B);
  u16* w2b = (u16*)(ws + OFF_W2B);
  u16* qb  = (u16*)(ws + OFF_Q);
  u16* kb  = (u16*)(ws + OFF_K);
  u16* vtb = (u16*)(ws + OFF_VT);
  u16* ctxb = (u16*)(ws + OFF_CTX);
  u16* y0 = (u16*)(ws + OFF_Y);
  u16* y1 = (u16*)(ws + OFF_Q);     // reuses q region (free after attention)
  u16* hb  = (u16*)(ws + OFF_HB);
  u16* m1b = (u16*)(ws + OFF_M1B);

  // 1. single fused cast launch (x + 6 weights)
  {
    const int n4 = (M_ROWS * D) / 4 + (D4 * D) / 4 * 2 + (D * D) / 4 * 4;  // 1835008
    cast_all_kernel<<<(n4 + 255) / 256, 256, 0, stream>>>(
        (const float4*)x, (const float4*)W1, (const float4*)W2, (const float4*)Wq,
        (const float4*)Wk, (const float4*)Wv, (const float4*)Wo,
        (ushort4*)xb, (ushort4*)w1b, (ushort4*)w2b, (ushort4*)wqb,
        (ushort4*)wkb, (ushort4*)wvb, (ushort4*)wob);
  }

  // 2. QKV projections (pipelined staging; q pre-scaled by QSCALE; V key-permuted)
  qkv_gemm<<<dim3(D / 128, M_ROWS / 128, 3), 256, 0, stream>>>(xb, wqb, wkb, wvb, qb, kb, vtb);

  // 3. attention: 512 blocks x 8 waves, 2 blocks/CU, 2-tile super-iterations
  attn_kernel<<<B * H * S / 32 / 4, 512, 0, stream>>>(qb, kb, vtb, ctxb);

  // 4. out-proj: split-K=2 -> y0,y1 bf16 partials; 512 blocks 2/CU (pipelined)
  gemm_bt<0, 1><<<dim3(D / 128, M_ROWS / 128, 2), 256, 0, stream>>>(
      ctxb, wob, nullptr, y0, y1, M_ROWS, D, D, D / 2);

  // 5. h = LN(xb + y0 + y1) -> bf16 hb
  ln_kernel<0><<<M_ROWS / 4, 256, 0, stream>>>(
      xb, y0, y1, nullptr, g1, bb1, nullptr, hb);

  // 6. m1 = relu(h @ W1.T + b1) -> bf16; 1024 blocks 4/CU
  gemm_bt<1, 0><<<dim3(D4 / 128, M_ROWS / 128, 1), 256, 0, stream>>>(
      hb, w1b, b1, m1b, nullptr, M_ROWS, D4, D, D);

  // 7. mlp partials: split-K=2 over K=2048 -> y0,y1 bf16; 512 blocks 2/CU
  gemm_bt<0, 1><<<dim3(D / 128, M_ROWS / 128, 2), 256, 0, stream>>>(
      m1b, w2b, nullptr, y0, y1, M_ROWS, D, D4, D4 / 2);

  // 8. out = LN(hb + y0 + y1 + b2)   (b2 folded in as pre-bias)
  ln_kernel<1><<<M_ROWS / 4, 256, 0, stream>>>(
      hb, y0, y1, b2, g2, bb2, (float*)d_out, nullptr);
}

// Round 12
// 246.861 us; speedup vs baseline: 1.0545x; 1.0019x over previous
//
#include <hip/hip_runtime.h>
#include <hip/hip_bf16.h>
#include <cstdint>
#include <cstddef>

// ---------- types ----------
typedef short bf16x8 __attribute__((ext_vector_type(8)));   // 8 bf16 (4 VGPRs) MFMA A/B frag
typedef float floatx4 __attribute__((ext_vector_type(4)));  // MFMA C/D frag
typedef unsigned int uintx4 __attribute__((ext_vector_type(4)));
typedef unsigned short u16;

// Problem constants
constexpr int B = 4, S = 2048, D = 512, H = 8, DH = 64;
constexpr int M_ROWS = B * S;          // 8192
constexpr int D4 = 4 * D;              // 2048
// Q pre-scale: 1/sqrt(DH) * log2(e) so attention uses exp2 directly
constexpr float QSCALE = 0.18033688011112042f;

__device__ __forceinline__ u16 f2b(float f) {
  unsigned u = __builtin_bit_cast(unsigned, f);
  u += 0x7fff + ((u >> 16) & 1);       // RNE
  return (u16)(u >> 16);
}

__device__ __forceinline__ float b2f(u16 h) {
  return __builtin_bit_cast(float, (unsigned)h << 16);
}

__device__ __forceinline__ bf16x8 ldfrag(const u16* p) {
  return *reinterpret_cast<const bf16x8*>(p);
}

__device__ __forceinline__ floatx4 mfma16(bf16x8 a, bf16x8 b, floatx4 c) {
  return __builtin_amdgcn_mfma_f32_16x16x32_bf16(a, b, c, 0, 0, 0);
}

__device__ __forceinline__ ushort4 f2b4(float4 v) {
  ushort4 r;
  r.x = f2b(v.x); r.y = f2b(v.y); r.z = f2b(v.z); r.w = f2b(v.w);
  return r;
}

// async global->LDS, 16B per lane; LDS dest = wave-uniform base + lane*16
__device__ __forceinline__ void gld16(const u16* g, u16* l) {
  __builtin_amdgcn_global_load_lds(
      (const __attribute__((address_space(1))) void*)g,
      (__attribute__((address_space(3))) void*)l, 16, 0, 0);
}

// add 8 bf16 (16B aligned) into v[8]
__device__ __forceinline__ void add8bf(const u16* p, float* v) {
  const ushort4 h0 = *(const ushort4*)p, h1 = *(const ushort4*)(p + 4);
  v[0] += b2f(h0.x); v[1] += b2f(h0.y); v[2] += b2f(h0.z); v[3] += b2f(h0.w);
  v[4] += b2f(h1.x); v[5] += b2f(h1.y); v[6] += b2f(h1.z); v[7] += b2f(h1.w);
}

// ---------- single fused cast launch: x, W1, W2, Wq, Wk, Wv, Wo ----------
__global__ void cast_all_kernel(const float4* __restrict__ x,
                                const float4* __restrict__ w1, const float4* __restrict__ w2,
                                const float4* __restrict__ wq, const float4* __restrict__ wk,
                                const float4* __restrict__ wv, const float4* __restrict__ wo,
                                ushort4* __restrict__ xb,
                                ushort4* __restrict__ w1b, ushort4* __restrict__ w2b,
                                ushort4* __restrict__ wqb, ushort4* __restrict__ wkb,
                                ushort4* __restrict__ wvb, ushort4* __restrict__ wob) {
  int i = blockIdx.x * blockDim.x + threadIdx.x;
  constexpr int NX = (M_ROWS * D) / 4;   // 1048576
  constexpr int N1 = (D4 * D) / 4;       // 262144
  constexpr int NS = (D * D) / 4;        // 65536
  if (i < NX) { xb[i] = f2b4(x[i]); return; }
  i -= NX;
  if (i < N1) { w1b[i] = f2b4(w1[i]); return; }
  i -= N1;
  if (i < N1) { w2b[i] = f2b4(w2[i]); return; }
  i -= N1;
  const int sel = i >> 16, off = i & (NS - 1);
  const float4* src = sel == 0 ? wq : sel == 1 ? wk : sel == 2 ? wv : wo;
  ushort4* dst = sel == 0 ? wqb : sel == 1 ? wkb : sel == 2 ? wvb : wob;
  dst[off] = f2b4(src[off]);
}

// ---------- staged GEMM  y = A @ W.T ----------
// PIPE=1: 3-buffer counted-vmcnt pipeline. PIPE=0: 2-buffer __syncthreads path.
// EPI=0: plain bf16 output, EPI=1: +bias, relu, bf16 (R7 split-K partials).
// R12: XCD-aware chunked block swizzle (T1, m157/m204 bijective form). With
// x-fastest default ordering, the NX blocks sharing an A row-panel round-robin
// onto NX different XCDs, so each panel is filled into multiple XCD L2s
// (mlp2: A read 4x, mlp1: 8x). The 1D chunked remap makes panel-sharing
// blocks consecutive -> same XCD -> each panel cached once per XCD.
// NWG = NX * 64 * NZ, divisible by 8 for all three instantiations.
template <int EPI, int PIPE, int NX, int NZ>
__global__ __launch_bounds__(256) void gemm_bt(
    const u16* __restrict__ A, const u16* __restrict__ W,
    const float* __restrict__ bias, void* __restrict__ out0, void* __restrict__ out1,
    int M, int N, int K, int klen) {
  __shared__ __align__(16) u16 As[PIPE ? 3 : 2][128 * 32];
  __shared__ __align__(16) u16 Bs[PIPE ? 3 : 2][128 * 32];
  const int wave = threadIdx.x >> 6, lane = threadIdx.x & 63;
  const int quad = lane >> 4, l16 = lane & 15;

  // chunked XCD swizzle: hw block b -> logical (b&7)*(NWG/8) + (b>>3);
  // logical order: y outer, z middle, x inner (x,z-groups share A data).
  constexpr int NWG = NX * 64 * NZ;
  int wg = blockIdx.x;
  wg = (wg & 7) * (NWG / 8) + (wg >> 3);
  const int xcol = wg % NX;
  const int zz = (wg / NX) % NZ;
  const int yrow = wg / (NX * NZ);

  const int rowB = yrow * 128, colB = xcol * 128;
  const int rowW = (wave >> 1) * 64, colW = (wave & 1) * 64;
  const int koff = zz * klen;
  void* out = zz ? out1 : out0;

  floatx4 acc[4][4];
#pragma unroll
  for (int i = 0; i < 4; i++)
#pragma unroll
    for (int j = 0; j < 4; j++) acc[i][j] = (floatx4){0.f,0.f,0.f,0.f};

  const u16* gA = A + (size_t)(rowB + wave * 32 + (lane >> 2)) * K + koff + (lane & 3) * 8;
  const u16* gB = W + (size_t)(colB + wave * 32 + (lane >> 2)) * K + koff + (lane & 3) * 8;
  const int lds_off = wave * 1024;

  if constexpr (PIPE) {
    const int nt = klen / 32;
#pragma unroll
    for (int T = 0; T < 2; T++) {
      gld16(gA + T * 32,                    &As[T][lds_off]);
      gld16(gA + (size_t)16 * K + T * 32,   &As[T][lds_off + 512]);
      gld16(gB + T * 32,                    &Bs[T][lds_off]);
      gld16(gB + (size_t)16 * K + T * 32,   &Bs[T][lds_off + 512]);
    }
    int rb = 0, wb = 2;
    for (int it = 0; it < nt; ++it) {
      if (it + 1 < nt) asm volatile("s_waitcnt vmcnt(4)" ::: "memory");
      else             asm volatile("s_waitcnt vmcnt(0)" ::: "memory");
      __builtin_amdgcn_s_barrier();
      __builtin_amdgcn_sched_barrier(0);

      if (it + 2 < nt) {
        const int kc2 = (it + 2) * 32;
        gld16(gA + kc2,                    &As[wb][lds_off]);
        gld16(gA + (size_t)16 * K + kc2,   &As[wb][lds_off + 512]);
        gld16(gB + kc2,                    &Bs[wb][lds_off]);
        gld16(gB + (size_t)16 * K + kc2,   &Bs[wb][lds_off + 512]);
      }

      bf16x8 a[4], b[4];
#pragma unroll
      for (int i = 0; i < 4; i++)
        a[i] = ldfrag(&As[rb][(rowW + i * 16 + l16) * 32 + quad * 8]);
#pragma unroll
      for (int j = 0; j < 4; j++)
        b[j] = ldfrag(&Bs[rb][(colW + j * 16 + l16) * 32 + quad * 8]);
#pragma unroll
      for (int i = 0; i < 4; i++)
#pragma unroll
        for (int j = 0; j < 4; j++) acc[i][j] = mfma16(a[i], b[j], acc[i][j]);

      rb = rb == 2 ? 0 : rb + 1;
      wb = wb == 2 ? 0 : wb + 1;
    }
  } else {
#pragma unroll
    for (int rr = 0; rr < 2; rr++) {
      gld16(gA + (size_t)rr * 16 * K, &As[0][lds_off + rr * 512]);
      gld16(gB + (size_t)rr * 16 * K, &Bs[0][lds_off + rr * 512]);
    }

    int buf = 0;
    for (int kc = 0; kc < klen; kc += 32, buf ^= 1) {
      __syncthreads();

      if (kc + 32 < klen) {
#pragma unroll
        for (int rr = 0; rr < 2; rr++) {
          gld16(gA + (size_t)rr * 16 * K + kc + 32, &As[buf ^ 1][lds_off + rr * 512]);
          gld16(gB + (size_t)rr * 16 * K + kc + 32, &Bs[buf ^ 1][lds_off + rr * 512]);
        }
      }

      bf16x8 a[4], b[4];
#pragma unroll
      for (int i = 0; i < 4; i++)
        a[i] = ldfrag(&As[buf][(rowW + i * 16 + l16) * 32 + quad * 8]);
#pragma unroll
      for (int j = 0; j < 4; j++)
        b[j] = ldfrag(&Bs[buf][(colW + j * 16 + l16) * 32 + quad * 8]);
#pragma unroll
      for (int i = 0; i < 4; i++)
#pragma unroll
        for (int j = 0; j < 4; j++) acc[i][j] = mfma16(a[i], b[j], acc[i][j]);
    }
  }

#pragma unroll
  for (int i = 0; i < 4; i++) {
#pragma unroll
    for (int j = 0; j < 4; j++) {
      const int gn = colB + colW + j * 16 + l16;
      const float bv = (EPI == 1) ? bias[gn] : 0.f;
#pragma unroll
      for (int r = 0; r < 4; r++) {
        const int gm = rowB + rowW + i * 16 + quad * 4 + r;
        float v = acc[i][j][r] + bv;
        if (EPI == 1) v = v > 0.f ? v : 0.f;
        ((u16*)out)[(size_t)gm * N + gn] = f2b(v);
      }
    }
  }
}

// ---------- staged fused QKV GEMM (3-buffer counted-vmcnt pipeline) ----------
// V is written KEY-PERMUTED within each aligned 64-key block:
//   slot sigma(k) holds key k,  sigma: [a b q1 q0 r1 r0] -> [a q1 q0 b r1 r0]
// R12: 1D grid with the `which` axis folded into the fast dimension, then the
// chunked XCD swizzle -- all 12 blocks (3 weights x 4 col-blocks) that read a
// given xb row-panel are consecutive -> same XCD -> panel cached once.
__global__ __launch_bounds__(256) void qkv_gemm(
    const u16* __restrict__ xb,
    const u16* __restrict__ wq, const u16* __restrict__ wk, const u16* __restrict__ wv,
    u16* __restrict__ q, u16* __restrict__ k, u16* __restrict__ vT) {
  __shared__ __align__(16) u16 As[3][128 * 32];
  __shared__ __align__(16) u16 Bs[3][128 * 32];
  const int wave = threadIdx.x >> 6, lane = threadIdx.x & 63;
  const int quad = lane >> 4, l16 = lane & 15;

  // chunked XCD swizzle over 768 blocks (chunk = 96/XCD)
  int wg = blockIdx.x;
  wg = (wg & 7) * 96 + (wg >> 3);
  const int yrow = wg / 12;
  const int r12 = wg % 12;
  const int which = r12 >> 2;
  const int xcol = r12 & 3;

  const u16* __restrict__ W = which == 0 ? wq : (which == 1 ? wk : wv);
  const int rowB = yrow * 128, colB = xcol * 128;
  const int rowW = (wave >> 1) * 64, colW = (wave & 1) * 64;

  floatx4 acc[4][4];
#pragma unroll
  for (int i = 0; i < 4; i++)
#pragma unroll
    for (int j = 0; j < 4; j++) acc[i][j] = (floatx4){0.f,0.f,0.f,0.f};

  const u16* gA = xb + (size_t)(rowB + wave * 32 + (lane >> 2)) * D + (lane & 3) * 8;
  const u16* gB = W + (size_t)(colB + wave * 32 + (lane >> 2)) * D + (lane & 3) * 8;
  const int lds_off = wave * 1024;

  constexpr int nt = D / 32;   // 16
#pragma unroll
  for (int T = 0; T < 2; T++) {
    gld16(gA + T * 32,                    &As[T][lds_off]);
    gld16(gA + (size_t)16 * D + T * 32,   &As[T][lds_off + 512]);
    gld16(gB + T * 32,                    &Bs[T][lds_off]);
    gld16(gB + (size_t)16 * D + T * 32,   &Bs[T][lds_off + 512]);
  }
  int rb = 0, wb = 2;
  for (int it = 0; it < nt; ++it) {
    if (it + 1 < nt) asm volatile("s_waitcnt vmcnt(4)" ::: "memory");
    else             asm volatile("s_waitcnt vmcnt(0)" ::: "memory");
    __builtin_amdgcn_s_barrier();
    __builtin_amdgcn_sched_barrier(0);

    if (it + 2 < nt) {
      const int kc2 = (it + 2) * 32;
      gld16(gA + kc2,                    &As[wb][lds_off]);
      gld16(gA + (size_t)16 * D + kc2,   &As[wb][lds_off + 512]);
      gld16(gB + kc2,                    &Bs[wb][lds_off]);
      gld16(gB + (size_t)16 * D + kc2,   &Bs[wb][lds_off + 512]);
    }

    bf16x8 a[4], b[4];
#pragma unroll
    for (int i = 0; i < 4; i++)
      a[i] = ldfrag(&As[rb][(rowW + i * 16 + l16) * 32 + quad * 8]);
#pragma unroll
    for (int j = 0; j < 4; j++)
      b[j] = ldfrag(&Bs[rb][(colW + j * 16 + l16) * 32 + quad * 8]);
#pragma unroll
    for (int i = 0; i < 4; i++)
#pragma unroll
      for (int j = 0; j < 4; j++) acc[i][j] = mfma16(a[i], b[j], acc[i][j]);

    rb = rb == 2 ? 0 : rb + 1;
    wb = wb == 2 ? 0 : wb + 1;
  }

  const float oscale = (which == 0) ? QSCALE : 1.0f;
  u16* dst01 = which == 0 ? q : k;
#pragma unroll
  for (int i = 0; i < 4; i++) {
#pragma unroll
    for (int j = 0; j < 4; j++) {
      const int gn = colB + colW + j * 16 + l16;   // output feature = h*64+dh
      const int h = gn >> 6, dh = gn & 63;
#pragma unroll
      for (int r = 0; r < 4; r++) {
        const int gm = rowB + rowW + i * 16 + quad * 4 + r;   // b*S + s
        const int bb = gm >> 11, s = gm & 2047;
        const u16 val = f2b(acc[i][j][r] * oscale);
        if (which < 2) {
          dst01[((((size_t)bb * H + h) * S) + s) * DH + dh] = val;
        } else {
          // sigma: keep bit5 + bits0-1; q=(s>>2)&3 -> bits3-4; b=(s>>4)&1 -> bit2
          const int sl = s & 63;
          const int sw = (s & ~63) | (sl & 35) | ((sl & 12) << 1) | ((sl & 16) >> 2);
          vT[((((size_t)bb * H + h) * DH) + dh) * S + sw] = val;
        }
      }
    }
  }
}

// ---------- flash attention: super-iteration (R9/R11, 47 us verified) ----------
// Swapped QK^T, V key-perm -> P in registers, R8 octet swizzle (conflicts 65K),
// 2-tile super-iters over a 4-buffer ring (one vmcnt+barrier per 64 keys).
__global__ __launch_bounds__(512, 4) void attn_kernel(
    const u16* __restrict__ q, const u16* __restrict__ k,
    const u16* __restrict__ vT, u16* __restrict__ ctxb) {
  __shared__ __align__(16) u16 kvbuf[4][2][4096];   // [buf][khalf][K 2048 | V 2048] 64 KB
  __shared__ __align__(16) float ltb[2][4][32];     // [khalf][pair][query] 1 KB
  const int wave = threadIdx.x >> 6, lane = threadIdx.x & 63;
  const int quad = lane >> 4, l16 = lane & 15;
  const int pair = wave >> 1, khalf = wave & 1;
  // XCD swizzle: 64 consecutive blk per XCD -> 4 bh (2 MB K/V) per XCD L2
  const int blk = (blockIdx.x & 7) * 64 + (blockIdx.x >> 3);
  const int w = blk * 4 + pair;          // 32-query tile id (4 | 64 -> same bh)
  const int bh = w >> 6, qt = w & 63;
  const int bb = bh >> 3, h = bh & 7;

  // Q fragments (B operand of swapped QK): 32 queries
  const u16* qp = q + ((size_t)bh * S + qt * 32 + l16) * DH + quad * 8;
  bf16x8 qf[2][2];
#pragma unroll
  for (int t = 0; t < 2; t++) {
    qf[t][0] = ldfrag(qp + (size_t)t * 16 * DH);
    qf[t][1] = ldfrag(qp + (size_t)t * 16 * DH + 32);
  }

  // staging role: pair<2 -> K (ch = pair&1 selects dh 0-31 / 32-63 half),
  //               pair>=2 -> V (ch selects dh rows 0-31 / 32-63)
  // soct: bank-conflict pre-swizzle of the source octet (R8, verified 65x
  // conflict reduction): LDS slot s of row r holds global octet s^((r>>1)&3).
  const int ch = pair & 1;
  const int soct = ((lane & 3) ^ ((lane >> 3) & 3)) * 8;
  const u16 *g0, *g1;
  size_t gstride;
  int d0;
  if (pair < 2) {
    g0 = k + (size_t)bh * S * DH + (size_t)(khalf * 1024 + (lane >> 2)) * DH
           + ch * 32 + soct;
    g1 = g0 + (size_t)16 * DH;
    gstride = (size_t)32 * DH;
    d0 = ch * 1024;                      // K region [0,2048): lo | hi
  } else {
    g0 = vT + (size_t)bh * DH * S + (size_t)(ch * 32 + (lane >> 2)) * S
            + khalf * 1024 + soct;
    g1 = g0 + (size_t)16 * S;
    gstride = 32;
    d0 = 2048 + ch * 1024;               // V region [2048,4096)
  }

  floatx4 o[2][4];
#pragma unroll
  for (int t = 0; t < 2; t++)
#pragma unroll
    for (int c = 0; c < 4; c++) o[t][c] = (floatx4){0.f,0.f,0.f,0.f};
  float lacc[2] = {0.f, 0.f};

  // prologue: stage tiles 0,1 into bufs 0,1
  gld16(g0,           &kvbuf[0][khalf][d0]);
  gld16(g1,           &kvbuf[0][khalf][d0 + 512]);
  gld16(g0 + gstride, &kvbuf[1][khalf][d0]);
  gld16(g1 + gstride, &kvbuf[1][khalf][d0 + 512]);

  // read-side swizzled slot: quad ^ ((l16>>1)&3), uniform for all 8 fragments
  const int sq = (quad ^ ((l16 >> 1) & 3)) * 8;

  for (int it2 = 0; it2 < 16; ++it2) {
    // own 4 loads (tiles 2*it2, 2*it2+1) must land; they are a full super-iter
    // old so this drain is cheap. Barrier then publishes both tiles block-wide.
    asm volatile("s_waitcnt vmcnt(0)" ::: "memory");
    __builtin_amdgcn_s_barrier();
    __builtin_amdgcn_sched_barrier(0);
    const int b0 = (it2 & 1) * 2;        // this super-iter's bufs {b0, b0+1}

    if (it2 + 1 < 16) {                  // prefetch tiles 2*it2+2, 2*it2+3
      const size_t t2 = (size_t)(2 * it2 + 2);
      gld16(g0 + t2 * gstride,       &kvbuf[b0 ^ 2][khalf][d0]);
      gld16(g1 + t2 * gstride,       &kvbuf[b0 ^ 2][khalf][d0 + 512]);
      gld16(g0 + (t2 + 1) * gstride, &kvbuf[(b0 ^ 2) + 1][khalf][d0]);
      gld16(g1 + (t2 + 1) * gstride, &kvbuf[(b0 ^ 2) + 1][khalf][d0 + 512]);
    }

#pragma unroll
    for (int half = 0; half < 2; ++half) {
      const u16* Kb = &kvbuf[b0 + half][khalf][0];
      const u16* Vb = &kvbuf[b0 + half][khalf][2048];
      bf16x8 kf[4], vf[4];
      kf[0] = ldfrag(&Kb[l16 * 32 + sq]);               // keys 0-15, dh lo
      kf[1] = ldfrag(&Kb[1024 + l16 * 32 + sq]);        // keys 0-15, dh hi
      kf[2] = ldfrag(&Kb[(16 + l16) * 32 + sq]);        // keys 16-31, lo
      kf[3] = ldfrag(&Kb[1024 + (16 + l16) * 32 + sq]); // keys 16-31, hi
#pragma unroll
      for (int c = 0; c < 4; c++)
        vf[c] = ldfrag(&Vb[(c * 16 + l16) * 32 + sq]);  // dh c*16+l16

      // QK^T (swapped) -> exp2 -> in-register pack -> PV, per 16-query sub-tile
#pragma unroll
      for (int t = 0; t < 2; t++) {
        floatx4 sc[2];
#pragma unroll
        for (int i = 0; i < 2; i++) {
          floatx4 z = (floatx4){0.f,0.f,0.f,0.f};
          z = mfma16(kf[2 * i], qf[t][0], z);
          z = mfma16(kf[2 * i + 1], qf[t][1], z);
          sc[i] = z;   // P^T[key = i*16+quad*4+r][query = t*16+l16]
        }

        unsigned wd[4];
        float a = 0.f;
#pragma unroll
        for (int i = 0; i < 2; i++) {
          const float p0 = __builtin_amdgcn_exp2f(sc[i][0]);
          const float p1 = __builtin_amdgcn_exp2f(sc[i][1]);
          const float p2 = __builtin_amdgcn_exp2f(sc[i][2]);
          const float p3 = __builtin_amdgcn_exp2f(sc[i][3]);
          a += (p0 + p1) + (p2 + p3);
          wd[2 * i] = __builtin_amdgcn_perm(
              __builtin_bit_cast(unsigned, p1) + 0x8000u,
              __builtin_bit_cast(unsigned, p0) + 0x8000u, 0x07060302u);
          wd[2 * i + 1] = __builtin_amdgcn_perm(
              __builtin_bit_cast(unsigned, p3) + 0x8000u,
              __builtin_bit_cast(unsigned, p2) + 0x8000u, 0x07060302u);
        }
        lacc[t] += a;
        // V key-permuted at write time -> this IS the PV A-fragment (keys 0-31)
        const uintx4 lo4 = (uintx4){wd[0], wd[1], wd[2], wd[3]};
        const bf16x8 pa = __builtin_bit_cast(bf16x8, lo4);

#pragma unroll
        for (int c = 0; c < 4; c++)
          o[t][c] = mfma16(pa, vf[c], o[t][c]);
      }
    }
  }

  // per-wave l totals (sum over quads; lt[t] uniform across quads)
  float lt[2];
#pragma unroll
  for (int t = 0; t < 2; t++) {
    float l = lacc[t];
    l += __shfl_xor(l, 16);
    l += __shfl_xor(l, 32);
    lt[t] = l;
  }

  // additive key-half combine overlaid on dead kvbuf (32 KB <= 64 KB).
  // XOR slot swizzle breaks the one-column 64-way bank conflict.
  __syncthreads();   // all kvbuf reads (final tiles) complete before overwrite
  float* ob = reinterpret_cast<float*>(&kvbuf[0][0][0]) + pair * 2048;
  if (quad == 0) {
#pragma unroll
    for (int t = 0; t < 2; t++) ltb[khalf][pair][t * 16 + l16] = lt[t];
  }
  if (khalf == 1) {
#pragma unroll
    for (int t = 0; t < 2; t++)
#pragma unroll
      for (int c = 0; c < 4; c++) {
        const int idx = 4 * t + c;
        const int slot = (idx ^ (lane & 7)) & 7;
        *reinterpret_cast<floatx4*>(&ob[lane * 32 + slot * 4]) = o[t][c];
      }
  }
  __syncthreads();
  if (khalf == 0) {
    float inv[2][4];
#pragma unroll
    for (int t = 0; t < 2; t++)
#pragma unroll
      for (int r = 0; r < 4; r++)
        inv[t][r] = 1.0f / (ltb[0][pair][t * 16 + quad * 4 + r] +
                            ltb[1][pair][t * 16 + quad * 4 + r]);

    const size_t crow_base = ((size_t)bb * S) * D + h * DH;
#pragma unroll
    for (int t = 0; t < 2; t++)
#pragma unroll
      for (int c = 0; c < 4; c++) {
        const int idx = 4 * t + c;
        const int slot = (idx ^ (lane & 7)) & 7;
        const floatx4 oo = o[t][c] +
            *reinterpret_cast<const floatx4*>(&ob[lane * 32 + slot * 4]);
        const int dh = c * 16 + l16;
#pragma unroll
        for (int r = 0; r < 4; r++) {
          const int s = qt * 32 + t * 16 + quad * 4 + r;
          ctxb[crow_base + (size_t)s * D + dh] = f2b(oo[r] * inv[t][r]);
        }
      }
  }
}

// ---------- layernorm ----------
// ya/yb are bf16 partials (split-K GEMM outputs).
// MODE 0 (LN1): resid bf16 (xb), out = bf16 hb
// MODE 1 (LN2): resid bf16 (hb), + b2 pre-bias, out = fp32 d_out
template <int MODE>
__global__ __launch_bounds__(256) void ln_kernel(
    const void* __restrict__ resid, const u16* __restrict__ ya,
    const u16* __restrict__ yb, const float* __restrict__ pb,
    const float* __restrict__ g, const float* __restrict__ bvec,
    float* __restrict__ outF, u16* __restrict__ outB) {
  const int wave = threadIdx.x >> 6, lane = threadIdx.x & 63;
  const int row = blockIdx.x * 4 + wave;
  float v[8] = {0.f, 0.f, 0.f, 0.f, 0.f, 0.f, 0.f, 0.f};
  add8bf(ya + (size_t)row * D + lane * 8, v);
  add8bf(yb + (size_t)row * D + lane * 8, v);
  add8bf((const u16*)resid + (size_t)row * D + lane * 8, v);
  if (MODE == 1) {
    const float4 p0 = *(const float4*)(pb + lane * 8);
    const float4 p1 = *(const float4*)(pb + lane * 8 + 4);
    v[0] += p0.x; v[1] += p0.y; v[2] += p0.z; v[3] += p0.w;
    v[4] += p1.x; v[5] += p1.y; v[6] += p1.z; v[7] += p1.w;
  }
  float sum = 0.f;
#pragma unroll
  for (int i = 0; i < 8; i++) sum += v[i];
#pragma unroll
  for (int d = 1; d < 64; d <<= 1) sum += __shfl_xor(sum, d);
  const float mu = sum * (1.f / D);
  float vs = 0.f;
#pragma unroll
  for (int i = 0; i < 8; i++) { const float t = v[i] - mu; vs += t * t; }
#pragma unroll
  for (int d = 1; d < 64; d <<= 1) vs += __shfl_xor(vs, d);
  const float rstd = rsqrtf(vs * (1.f / D) + 1e-5f);
#pragma unroll
  for (int i = 0; i < 8; i++) {
    const int col = lane * 8 + i;
    const float o = (v[i] - mu) * rstd * g[col] + bvec[col];
    if (MODE == 0) outB[(size_t)row * D + col] = f2b(o);
    else           outF[(size_t)row * D + col] = o;
  }
}

// ---------- workspace layout (bytes) ----------
constexpr size_t OFF_XB  = 0;                       // 8 MB  xb [8192,512] bf16
constexpr size_t OFF_WQB = 8u << 20;                // 512 KB
constexpr size_t OFF_WKB = OFF_WQB + (512u << 10);
constexpr size_t OFF_WVB = OFF_WKB + (512u << 10);
constexpr size_t OFF_WOB = OFF_WVB + (512u << 10);
constexpr size_t OFF_W1B = 10u << 20;               // 2 MB
constexpr size_t OFF_W2B = 12u << 20;               // 2 MB
constexpr size_t OFF_Q   = 14u << 20;               // 8 MB  (reused as y1 bf16 after attn)
constexpr size_t OFF_K   = 22u << 20;               // 8 MB
constexpr size_t OFF_VT  = 30u << 20;               // 8 MB
constexpr size_t OFF_CTX = 38u << 20;               // 8 MB
constexpr size_t OFF_Y   = 46u << 20;               // 8 MB bf16 (y0)
constexpr size_t OFF_HB  = 78u << 20;               // 8 MB bf16 h
constexpr size_t OFF_M1B = 86u << 20;               // 32 MB bf16 [8192,2048]
// total 118 MB

extern "C" void kernel_launch(void* const* d_in, const int* in_sizes, int n_in,
                              void* d_out, int out_size, void* d_ws, size_t ws_size,
                              hipStream_t stream) {
  const float* x  = (const float*)d_in[0];
  const float* Wq = (const float*)d_in[1];
  const float* Wk = (const float*)d_in[2];
  const float* Wv = (const float*)d_in[3];
  const float* Wo = (const float*)d_in[4];
  const float* W1 = (const float*)d_in[5];
  const float* b1 = (const float*)d_in[6];
  const float* W2 = (const float*)d_in[7];
  const float* b2 = (const float*)d_in[8];
  const float* g1 = (const float*)d_in[9];
  const float* bb1 = (const float*)d_in[10];
  const float* g2 = (const float*)d_in[11];
  const float* bb2 = (const float*)d_in[12];

  char* ws = (char*)d_ws;
  u16* xb  = (u16*)(ws + OFF_XB);
  u16* wqb = (u16*)(ws + OFF_WQB);
  u16* wkb = (u16*)(ws + OFF_WKB);
  u16* wvb = (u16*)(ws + OFF_WVB);
  u16* wob = (u16*)(ws + OFF_WOB);
  u16* w1b = (u16*)(ws + OFF_W1B);
  u16* w2b = (u16*)(ws + OFF_W2B);
  u16* qb  = (u16*)(ws + OFF_Q);
  u16* kb  = (u16*)(ws + OFF_K);
  u16* vtb = (u16*)(ws + OFF_VT);
  u16* ctxb = (u16*)(ws + OFF_CTX);
  u16* y0 = (u16*)(ws + OFF_Y);
  u16* y1 = (u16*)(ws + OFF_Q);     // reuses q region (free after attention)
  u16* hb  = (u16*)(ws + OFF_HB);
  u16* m1b = (u16*)(ws + OFF_M1B);

  // 1. single fused cast launch (x + 6 weights)
  {
    const int n4 = (M_ROWS * D) / 4 + (D4 * D) / 4 * 2 + (D * D) / 4 * 4;  // 1835008
    cast_all_kernel<<<(n4 + 255) / 256, 256, 0, stream>>>(
        (const float4*)x, (const float4*)W1, (const float4*)W2, (const float4*)Wq,
        (const float4*)Wk, (const float4*)Wv, (const float4*)Wo,
        (ushort4*)xb, (ushort4*)w1b, (ushort4*)w2b, (ushort4*)wqb,
        (ushort4*)wkb, (ushort4*)wvb, (ushort4*)wob);
  }

  // 2. QKV projections (pipelined; q pre-scaled; V key-permuted; XCD-chunked)
  qkv_gemm<<<768, 256, 0, stream>>>(xb, wqb, wkb, wvb, qb, kb, vtb);

  // 3. attention: 512 blocks x 8 waves, 2 blocks/CU, 2-tile super-iterations
  attn_kernel<<<B * H * S / 32 / 4, 512, 0, stream>>>(qb, kb, vtb, ctxb);

  // 4. out-proj: split-K=2 -> y0,y1 bf16 partials; XCD-chunked 512 blocks
  gemm_bt<0, 1, 4, 2><<<512, 256, 0, stream>>>(
      ctxb, wob, nullptr, y0, y1, M_ROWS, D, D, D / 2);

  // 5. h = LN(xb + y0 + y1) -> bf16 hb
  ln_kernel<0><<<M_ROWS / 4, 256, 0, stream>>>(
      xb, y0, y1, nullptr, g1, bb1, nullptr, hb);

  // 6. m1 = relu(h @ W1.T + b1) -> bf16; XCD-chunked 1024 blocks 4/CU
  gemm_bt<1, 0, 16, 1><<<1024, 256, 0, stream>>>(
      hb, w1b, b1, m1b, nullptr, M_ROWS, D4, D, D);

  // 7. mlp partials: split-K=2 over K=2048 -> y0,y1 bf16; XCD-chunked 512 blocks
  gemm_bt<0, 1, 4, 2><<<512, 256, 0, stream>>>(
      m1b, w2b, nullptr, y0, y1, M_ROWS, D, D4, D4 / 2);

  // 8. out = LN(hb + y0 + y1 + b2)   (b2 folded in as pre-bias)
  ln_kernel<1><<<M_ROWS / 4, 256, 0, stream>>>(
      hb, y0, y1, b2, g2, bb2, (float*)d_out, nullptr);
}